// Round 7
// baseline (11772.726 us; speedup 1.0000x reference)
//
#include <hip/hip_runtime.h>

typedef unsigned short u16;
typedef unsigned int   u32;

static __device__ __forceinline__ u16 f2bf(float f){
  u32 u = __float_as_uint(f);
  u32 r = u + 0x7fffu + ((u>>16)&1u);   // RNE
  return (u16)(r>>16);
}
static __device__ __forceinline__ float sigf (float x){ return 1.0f/(1.0f+__expf(-x)); }
static __device__ __forceinline__ float tanh_(float x){ return 2.0f/(1.0f+__expf(-2.0f*x)) - 1.0f; }

// sizes
#define NM 2730            // 273*10 distinct (t, j=b%10) rows
#define N_O0 878080        // 245*128*28
#define N_O3 978432        // 273*128*28

// scan4 weight split (per 64-k slice): 40 reg + 5 LDS + 19 streamed
#define RJJ 40
#define LJJ 5
#define SJJ 19

// ---- transpose f32 -> f32: dst[c*rows+r] = src[r*cols+c] ----
__global__ void k_trf(const float* __restrict__ src, float* __restrict__ dst, int rows, int cols){
  int i = blockIdx.x*256 + threadIdx.x;
  if(i >= rows*cols) return;
  int c = i / rows, r = i - c*rows;
  dst[i] = src[r*cols + c];
}

// ---- transpose f32 -> bf16: dst[c*rows+r] = bf16(src[r*cols+c]) ----
__global__ void k_trb(const float* __restrict__ src, u16* __restrict__ dst, int rows, int cols){
  int i = blockIdx.x*256 + threadIdx.x;
  if(i >= rows*cols) return;
  int c = i / rows, r = i - c*rows;
  dst[i] = f2bf(src[r*cols + c]);
}

// ---- x (128,300) f32 -> xT[t*128+b] f32 ----
__global__ void k_xT(const float* __restrict__ x, float* __restrict__ xT){
  int i = blockIdx.x*256 + threadIdx.x;
  if(i >= 300*128) return;
  int t = i >> 7, b = i & 127;
  xT[i] = x[b*300 + t];
}

// ---- exponential-smoothing scan: 128 threads, one per batch row ----
__global__ void k_es(const float* __restrict__ xT, const float* __restrict__ alpha,
                     const float* __restrict__ gamma, const float* __restrict__ iseas,
                     float* __restrict__ ST, float* __restrict__ lvlT){
  int b = threadIdx.x;
  float a = sigf(alpha[b]);
  float g = sigf(gamma[b]);
  float S0[7];
  #pragma unroll
  for(int i=0;i<7;i++){ S0[i] = __expf(iseas[b*7+i]); ST[i*128+b] = S0[i]; }
  ST[7*128+b] = S0[0];
  float q0=S0[1],q1=S0[2],q2=S0[3],q3=S0[4],q4=S0[5],q5=S0[6],q6=S0[0];
  float lvl = xT[b]/S0[0];
  lvlT[b] = lvl;
  for(int t=1;t<300;t++){
    float xt = xT[t*128+b];
    float s  = q0;
    lvl = a*(xt/s) + (1.0f-a)*lvl;
    float sn = g*(xt/lvl) + (1.0f-g)*s;
    q0=q1;q1=q2;q2=q3;q3=q4;q4=q5;q5=q6;q6=sn;
    lvlT[t*128+b]   = lvl;
    ST[(t+7)*128+b] = sn;
  }
}

// ---- build window_input for the 10 distinct rows: win[(t*10+j)*49 + f] ----
__global__ void k_win(const float* __restrict__ xT, const float* __restrict__ ST,
                      const float* __restrict__ lvlT, const float* __restrict__ cats,
                      const float* __restrict__ mp, float* __restrict__ win){
  int i = blockIdx.x*256 + threadIdx.x;
  if(i >= NM*49) return;
  int f = i % 49;
  int m = i / 49;
  int j = m % 10, t = m / 10;
  float v;
  if(f < 28){
    int c = t + f;
    v = xT[c*128 + j] / ST[c*128 + j] / lvlT[(t+27)*128 + j];
  } else if(f < 48){
    v = cats[j*20 + (f-28)];
  } else {
    v = mp[0];
  }
  win[i] = v;
}

// ---- actual_values (window_output), per real batch row b (f32 out) ----
__global__ void k_wout(const float* __restrict__ xT, const float* __restrict__ ST,
                       const float* __restrict__ lvlT, float* __restrict__ out1){
  int i = blockIdx.x*256 + threadIdx.x;
  if(i >= N_O0) return;
  int o = i % 28;
  int b = (i/28) % 128;
  int t = i/(28*128);
  int c = 28 + t + o;                    // L + t + o  (<= 299)
  out1[i] = xT[c*128+b] / ST[c*128+b] / lvlT[(27+t)*128+b];
}

// ---- batched xz = X @ WihT + b : block = 4 rows x 1024 gates, 256 threads ----
__global__ __launch_bounds__(256) void k_gemm(const float* __restrict__ X,
                                              const float* __restrict__ WT,   // [F][1024] f32
                                              const float* __restrict__ bias, // [1024] f32
                                              float* __restrict__ Z, int F){
  __shared__ float Xs[4][256];
  const int tid = threadIdx.x;
  const int m0 = blockIdx.x*4;
  for(int p=0;p<4;p++){
    int m = m0+p;
    for(int f=tid; f<F; f+=256)
      Xs[p][f] = (m < NM) ? X[m*F+f] : 0.0f;
  }
  __syncthreads();
  float acc0[4], acc1[4], acc2[4], acc3[4];
  {
    float b0 = bias[tid];
    float b1 = bias[tid+256];
    float b2 = bias[tid+512];
    float b3 = bias[tid+768];
    #pragma unroll
    for(int p=0;p<4;p++){ acc0[p]=b0; acc1[p]=b1; acc2[p]=b2; acc3[p]=b3; }
  }
  #pragma unroll 4
  for(int f=0; f<F; f++){
    float w0 = WT[f*1024 + tid      ];
    float w1 = WT[f*1024 + tid+256  ];
    float w2 = WT[f*1024 + tid+512  ];
    float w3 = WT[f*1024 + tid+768  ];
    #pragma unroll
    for(int p=0;p<4;p++){
      float xv = Xs[p][f];
      acc0[p] += w0*xv; acc1[p] += w1*xv; acc2[p] += w2*xv; acc3[p] += w3*xv;
    }
  }
  for(int p=0;p<4;p++){
    int m = m0+p;
    if(m < NM){
      float* zb = Z + m*1024 + tid;
      zb[0]=acc0[p]; zb[256]=acc1[p]; zb[512]=acc2[p]; zb[768]=acc3[p];
    }
  }
}

// ---- LSTM scan v4: one WG (512 thr) per chain; bf16 Whh split
// register (40/64) + LDS (5/64) + L2-stream (19/64). Thread (kg,js):
// gate-rows kg*8..+8, k-slice js*64..+64. Per step: partial dots ->
// zp -> combine (gate math, h/c update). Intra-WG syncs only.
__global__ __launch_bounds__(512, 2) void k_scan4(
    const float* __restrict__ Z,
    const u16* __restrict__ WT,   // [256][1024] bf16 (WhhT [k][row])
    float* __restrict__ Y,
    const float* __restrict__ RES,
    int d){
  __shared__ float h_lds[256];
  __shared__ float c_lds[256];
  __shared__ float zp[4][1024];          // 16 KB
  __shared__ u32   wl[LJJ*2048];         // 40 KB LDS-resident weights
  const int tid = threadIdx.x;
  const int chain = blockIdx.x;
  const int j = chain % 10;
  const int r = chain / 10;
  const int ns = (273 - r + d - 1)/d;
  const int kg = tid & 127;
  const int js = tid >> 7;

  // one-time weight staging (coalesced 16B loads)
  u32 wreg[RJJ*4];
  #pragma unroll
  for(int jj=0;jj<RJJ;jj++){
    uint4 w = *(const uint4*)(WT + (size_t)(js*64+jj)*1024 + kg*8);
    wreg[jj*4+0]=w.x; wreg[jj*4+1]=w.y; wreg[jj*4+2]=w.z; wreg[jj*4+3]=w.w;
  }
  #pragma unroll
  for(int lj=0;lj<LJJ;lj++){
    uint4 w = *(const uint4*)(WT + (size_t)(js*64+RJJ+lj)*1024 + kg*8);
    *(uint4*)&wl[lj*2048 + tid*4] = w;
  }
  const u16* Wstr = WT + (size_t)(js*64+RJJ+LJJ)*1024 + kg*8;

  if(tid < 256){ h_lds[tid] = 0.0f; c_lds[tid] = 0.0f; }
  __syncthreads();

  int t = r;
  for(int s=0; s<ns; s++, t+=d){
    float a0=0,a1=0,a2=0,a3=0,a4=0,a5=0,a6=0,a7=0;
    // streamed slice first (loads pipelined by unroll, consumed below VALU)
    #pragma unroll
    for(int c=0;c<SJJ;c++){
      uint4 w = *(const uint4*)(Wstr + (size_t)c*1024);
      float hv = h_lds[js*64 + RJJ + LJJ + c];
      a0 += __uint_as_float(w.x<<16)           * hv;
      a1 += __uint_as_float(w.x & 0xffff0000u) * hv;
      a2 += __uint_as_float(w.y<<16)           * hv;
      a3 += __uint_as_float(w.y & 0xffff0000u) * hv;
      a4 += __uint_as_float(w.z<<16)           * hv;
      a5 += __uint_as_float(w.z & 0xffff0000u) * hv;
      a6 += __uint_as_float(w.w<<16)           * hv;
      a7 += __uint_as_float(w.w & 0xffff0000u) * hv;
    }
    // LDS slice
    #pragma unroll
    for(int lj=0;lj<LJJ;lj++){
      uint4 w = *(const uint4*)&wl[lj*2048 + tid*4];
      float hv = h_lds[js*64 + RJJ + lj];
      a0 += __uint_as_float(w.x<<16)           * hv;
      a1 += __uint_as_float(w.x & 0xffff0000u) * hv;
      a2 += __uint_as_float(w.y<<16)           * hv;
      a3 += __uint_as_float(w.y & 0xffff0000u) * hv;
      a4 += __uint_as_float(w.z<<16)           * hv;
      a5 += __uint_as_float(w.z & 0xffff0000u) * hv;
      a6 += __uint_as_float(w.w<<16)           * hv;
      a7 += __uint_as_float(w.w & 0xffff0000u) * hv;
    }
    // register slice (pure ALU)
    {
      const float4* hp = (const float4*)(h_lds + js*64);
      #pragma unroll
      for(int q4=0;q4<RJJ/4;q4++){
        float4 h4 = hp[q4];
        #pragma unroll
        for(int e=0;e<4;e++){
          const int jj = q4*4+e;
          const float hv = (e==0)?h4.x:(e==1)?h4.y:(e==2)?h4.z:h4.w;
          u32 wx = wreg[jj*4+0], wy = wreg[jj*4+1], wz = wreg[jj*4+2], ww = wreg[jj*4+3];
          a0 += __uint_as_float(wx<<16)           * hv;
          a1 += __uint_as_float(wx & 0xffff0000u) * hv;
          a2 += __uint_as_float(wy<<16)           * hv;
          a3 += __uint_as_float(wy & 0xffff0000u) * hv;
          a4 += __uint_as_float(wz<<16)           * hv;
          a5 += __uint_as_float(wz & 0xffff0000u) * hv;
          a6 += __uint_as_float(ww<<16)           * hv;
          a7 += __uint_as_float(ww & 0xffff0000u) * hv;
        }
      }
    }
    float4* zr = (float4*)&zp[js][kg*8];
    zr[0] = make_float4(a0,a1,a2,a3);
    zr[1] = make_float4(a4,a5,a6,a7);
    __syncthreads();
    if(tid < 256){
      const int u = tid;
      const float* zb = Z + (size_t)(t*10 + j)*1024;
      float zi = zb[u]     + zp[0][u]     + zp[1][u]     + zp[2][u]     + zp[3][u];
      float zf = zb[u+256] + zp[0][u+256] + zp[1][u+256] + zp[2][u+256] + zp[3][u+256];
      float zg = zb[u+512] + zp[0][u+512] + zp[1][u+512] + zp[2][u+512] + zp[3][u+512];
      float zo = zb[u+768] + zp[0][u+768] + zp[1][u+768] + zp[2][u+768] + zp[3][u+768];
      float c  = sigf(zf)*c_lds[u] + sigf(zi)*tanh_(zg);
      float h  = sigf(zo)*tanh_(c);
      c_lds[u] = c; h_lds[u] = h;
      float o = h;
      if(RES) o += RES[(size_t)(t*10+j)*256 + u];
      Y[(size_t)(t*10+j)*256 + u] = o;
    }
    __syncthreads();
  }
}

// ---- head: h = tanh(y4 @ linW.T + lb); rnn = h @ scW.T + sb ----
__global__ __launch_bounds__(256) void k_head(const float* __restrict__ Y4,
    const float* __restrict__ LWT,  // [256][256] f32 (linWT: [f][u])
    const float* __restrict__ lb,
    const float* __restrict__ SWT,  // [256][28] f32  (scoreT: [f][o])
    const float* __restrict__ sb,
    float* __restrict__ R){
  __shared__ float v [8][256];
  __shared__ float h2[8][256];
  const int tid = threadIdx.x;
  const int m0 = blockIdx.x*8;
  for(int p=0;p<8;p++){
    int m = m0+p;
    v[p][tid] = (m<NM) ? Y4[m*256+tid] : 0.0f;
  }
  __syncthreads();
  float acc[8];
  float bz = lb[tid];
  #pragma unroll
  for(int p=0;p<8;p++) acc[p]=bz;
  #pragma unroll 4
  for(int f=0; f<256; f++){
    float w = LWT[f*256+tid];
    #pragma unroll
    for(int p=0;p<8;p++) acc[p] += w * v[p][f];
  }
  #pragma unroll
  for(int p=0;p<8;p++) h2[p][tid] = tanh_(acc[p]);
  __syncthreads();
  if(tid < 224){
    int o = tid % 28, p = tid / 28;
    int m = m0 + p;
    if(m < NM){
      float a = sb[o];
      for(int f=0; f<256; f++) a += SWT[f*28+o] * h2[p][f];
      R[m*28+o] = a;
    }
  }
}

// ---- final outputs (f32) ----
// S_ext = concat(S_full[0:307], S_full[300:307]); S_ext[-28:][o] =
//   S_full[286+o] (o<21) else S_full[279+o]
__global__ void k_out(const float* __restrict__ R, const float* __restrict__ ST,
                      const float* __restrict__ lvlT, const float* __restrict__ val,
                      float* __restrict__ out){
  int i = blockIdx.x*256 + threadIdx.x;
  float* o0 = out;                 // prediction_values (245,128,28)
  float* o2 = out + 1756160;       // holdout_prediction (128,28)
  float* o3 = out + 1759744;       // rnn_out (273,128,28)
  float* o4 = out + 2738176;       // hav (128,28)
  float* o5 = out + 2741760;       // hav_norm (128,28)
  if(i < N_O3){
    int o = i % 28;
    int b = (i/28) % 128;
    int t = i/(28*128);
    float vv = R[(t*10 + (b%10))*28 + o];
    o3[i] = vv;
    if(i < N_O0) o0[i] = vv;       // rnn_out[:-OUT], same linear layout
  }
  if(i < 128*28){
    int b = i/28, o = i%28;
    int col = (o < 21) ? (286+o) : (279+o);
    float Sm = ST[col*128 + b];
    float lv = lvlT[299*128 + b];
    float hv = R[(2720 + (b%10))*28 + o] * Sm * lv;
    o2[i] = (hv > 0.0f) ? hv : 0.0f;
    o4[i] = val[i];
    o5[i] = val[i] / Sm / lv;
  }
}

extern "C" void kernel_launch(void* const* d_in, const int* in_sizes, int n_in,
                              void* d_out, int out_size, void* d_ws, size_t ws_size,
                              hipStream_t stream){
  (void)in_sizes; (void)n_in; (void)out_size; (void)ws_size;
  const float* x     = (const float*)d_in[0];
  const float* val   = (const float*)d_in[1];
  const float* alpha = (const float*)d_in[2];
  const float* gamma = (const float*)d_in[3];
  const float* iseas = (const float*)d_in[4];
  const float* cats  = (const float*)d_in[5];
  const float* mp    = (const float*)d_in[6];
  const float* Wih[4]  = {(const float*)d_in[7],  (const float*)d_in[10], (const float*)d_in[13], (const float*)d_in[16]};
  const float* Whh[4]  = {(const float*)d_in[8],  (const float*)d_in[11], (const float*)d_in[14], (const float*)d_in[17]};
  const float* bias[4] = {(const float*)d_in[9],  (const float*)d_in[12], (const float*)d_in[15], (const float*)d_in[18]};
  const float* linW  = (const float*)d_in[19];
  const float* linb  = (const float*)d_in[20];
  const float* scW   = (const float*)d_in[21];
  const float* scb   = (const float*)d_in[22];

  // ---- workspace layout: f32 region, then 16B-aligned bf16 Whh region ----
  float* Fw   = (float*)d_ws;
  float* ST   = Fw;                 // 39296
  float* lvlT = ST   + 39296;       // 38400
  float* xT   = lvlT + 38400;       // 38400
  float* win  = xT   + 38400;       // 133776
  float* xz   = win  + 133776;      // 2795520
  float* yA   = xz   + 2795520;     // 698880  (L1 out / L3 out / L4 out)
  float* yB   = yA   + 698880;      // 698880  (L2 out, residual)
  float* rnn  = yB   + 698880;      // 76448
  float* wihT[4];
  wihT[0] = rnn + 76448;            // 50176
  wihT[1] = wihT[0] + 50176;        // 262144
  wihT[2] = wihT[1] + 262144;
  wihT[3] = wihT[2] + 262144;
  float* linWT = wihT[3] + 262144;  // 65536
  float* scT   = linWT + 65536;     // 7168
  u16*   WB16  = (u16*)(scT + 7168);           // f32 count %4==0 -> 16B aligned
  u16*   whhT[4];
  for(int l=0;l<4;l++) whhT[l] = WB16 + (size_t)l*262144;   // 4 * 512KB bf16

  // ---- weight prep ----
  for(int l=0;l<4;l++)
    k_trb<<<(262144+255)/256, 256, 0, stream>>>(Whh[l], whhT[l], 1024, 256);
  k_trf<<<(1024*49+255)/256, 256, 0, stream>>>(Wih[0], wihT[0], 1024, 49);
  for(int l=1;l<4;l++)
    k_trf<<<(262144+255)/256, 256, 0, stream>>>(Wih[l], wihT[l], 1024, 256);
  k_trf<<<(65536+255)/256, 256, 0, stream>>>(linW, linWT, 256, 256);
  k_trf<<<(7168+255)/256, 256, 0, stream>>>(scW, scT, 28, 256);

  // ---- ES scan + windows ----
  k_xT<<<150, 256, 0, stream>>>(x, xT);
  k_es<<<1, 128, 0, stream>>>(xT, alpha, gamma, iseas, ST, lvlT);
  k_win<<<(NM*49+255)/256, 256, 0, stream>>>(xT, ST, lvlT, cats, mp, win);
  k_wout<<<N_O0/256, 256, 0, stream>>>(xT, ST, lvlT, (float*)d_out + 878080);

  // ---- 4 LSTM layers: batched Wih GEMM + cached-weight scan ----
  const int    dlt[4]    = {1, 2, 2, 6};
  const int    chains[4] = {10, 20, 20, 60};
  const float* Xin[4]    = {win, yA, yB, yA};
  float*       Yout[4]   = {yA, yB, yA, yA};
  const int    Fdim[4]   = {49, 256, 256, 256};
  for(int l=0;l<4;l++){
    k_gemm<<<(NM+3)/4, 256, 0, stream>>>(Xin[l], wihT[l], bias[l], xz, Fdim[l]);
    k_scan4<<<chains[l], 512, 0, stream>>>(xz, whhT[l], Yout[l],
                                           (l==3) ? yB : (const float*)nullptr, dlt[l]);
  }

  // ---- head + outputs ----
  k_head<<<(NM+7)/8, 256, 0, stream>>>(yA, linWT, linb, scT, scb, rnn);
  k_out<<<N_O3/256, 256, 0, stream>>>(rnn, ST, lvlT, val, (float*)d_out);
}

// Round 8
// 2342.325 us; speedup vs baseline: 5.0261x; 5.0261x over previous
//
#include <hip/hip_runtime.h>
#include <hip/hip_fp16.h>

typedef unsigned short u16;
typedef unsigned int   u32;

static __device__ __forceinline__ float sigf (float x){ return 1.0f/(1.0f+__expf(-x)); }
static __device__ __forceinline__ float tanh_(float x){ return 2.0f/(1.0f+__expf(-2.0f*x)) - 1.0f; }

// sizes
#define NM 2730            // 273*10 distinct (t, j=b%10) rows
#define N_O0 878080        // 245*128*28
#define N_O3 978432        // 273*128*28

typedef _Float16 h2v __attribute__((ext_vector_type(2)));

static __device__ __forceinline__ float dot2(u32 w, u32 h, float acc){
#if __has_builtin(__builtin_amdgcn_fdot2)
  return __builtin_amdgcn_fdot2(__builtin_bit_cast(h2v, w), __builtin_bit_cast(h2v, h), acc, false);
#else
  h2v wv = __builtin_bit_cast(h2v, w);
  h2v hv = __builtin_bit_cast(h2v, h);
  return acc + (float)wv.x*(float)hv.x + (float)wv.y*(float)hv.y;
#endif
}

// ---- transpose f32 -> f32: dst[c*rows+r] = src[r*cols+c] ----
__global__ void k_trf(const float* __restrict__ src, float* __restrict__ dst, int rows, int cols){
  int i = blockIdx.x*256 + threadIdx.x;
  if(i >= rows*cols) return;
  int c = i / rows, r = i - c*rows;
  dst[i] = src[r*cols + c];
}

// ---- pack Whh[1024][256] f32 -> WQ layout for the scan (f16 pairs) ----
// u32 index i: pi=i&3, u4=i>>2; kg=u4&127; rr=(u4>>7)&7; pq=(u4>>10)&7; js=u4>>13
// row = rr*128+kg; k0 = js*64 + (pq*4+pi)*2
__global__ void k_pack(const float* __restrict__ W, u32* __restrict__ WQ){
  int i = blockIdx.x*256 + threadIdx.x;
  if(i >= 131072) return;
  int pi = i & 3;
  int u4 = i >> 2;
  int kg = u4 & 127;
  int rr = (u4 >> 7) & 7;
  int pq = (u4 >> 10) & 7;
  int js = u4 >> 13;
  int row = rr*128 + kg;
  int k0  = js*64 + (pq*4+pi)*2;
  __half a = __float2half(W[row*256 + k0]);
  __half b = __float2half(W[row*256 + k0 + 1]);
  WQ[i] = (u32)__half_as_ushort(a) | ((u32)__half_as_ushort(b) << 16);
}

// ---- x (128,300) f32 -> xT[t*128+b] f32 ----
__global__ void k_xT(const float* __restrict__ x, float* __restrict__ xT){
  int i = blockIdx.x*256 + threadIdx.x;
  if(i >= 300*128) return;
  int t = i >> 7, b = i & 127;
  xT[i] = x[b*300 + t];
}

// ---- exponential-smoothing scan: 128 threads, one per batch row ----
__global__ void k_es(const float* __restrict__ xT, const float* __restrict__ alpha,
                     const float* __restrict__ gamma, const float* __restrict__ iseas,
                     float* __restrict__ ST, float* __restrict__ lvlT){
  int b = threadIdx.x;
  float a = sigf(alpha[b]);
  float g = sigf(gamma[b]);
  float S0[7];
  #pragma unroll
  for(int i=0;i<7;i++){ S0[i] = __expf(iseas[b*7+i]); ST[i*128+b] = S0[i]; }
  ST[7*128+b] = S0[0];
  float q0=S0[1],q1=S0[2],q2=S0[3],q3=S0[4],q4=S0[5],q5=S0[6],q6=S0[0];
  float lvl = xT[b]/S0[0];
  lvlT[b] = lvl;
  for(int t=1;t<300;t++){
    float xt = xT[t*128+b];
    float s  = q0;
    lvl = a*(xt/s) + (1.0f-a)*lvl;
    float sn = g*(xt/lvl) + (1.0f-g)*s;
    q0=q1;q1=q2;q2=q3;q3=q4;q4=q5;q5=q6;q6=sn;
    lvlT[t*128+b]   = lvl;
    ST[(t+7)*128+b] = sn;
  }
}

// ---- build window_input for the 10 distinct rows: win[(t*10+j)*49 + f] ----
__global__ void k_win(const float* __restrict__ xT, const float* __restrict__ ST,
                      const float* __restrict__ lvlT, const float* __restrict__ cats,
                      const float* __restrict__ mp, float* __restrict__ win){
  int i = blockIdx.x*256 + threadIdx.x;
  if(i >= NM*49) return;
  int f = i % 49;
  int m = i / 49;
  int j = m % 10, t = m / 10;
  float v;
  if(f < 28){
    int c = t + f;
    v = xT[c*128 + j] / ST[c*128 + j] / lvlT[(t+27)*128 + j];
  } else if(f < 48){
    v = cats[j*20 + (f-28)];
  } else {
    v = mp[0];
  }
  win[i] = v;
}

// ---- actual_values (window_output), per real batch row b (f32 out) ----
__global__ void k_wout(const float* __restrict__ xT, const float* __restrict__ ST,
                       const float* __restrict__ lvlT, float* __restrict__ out1){
  int i = blockIdx.x*256 + threadIdx.x;
  if(i >= N_O0) return;
  int o = i % 28;
  int b = (i/28) % 128;
  int t = i/(28*128);
  int c = 28 + t + o;                    // L + t + o  (<= 299)
  out1[i] = xT[c*128+b] / ST[c*128+b] / lvlT[(27+t)*128+b];
}

// ---- batched xz = X @ WihT + b : block = 4 rows x 1024 gates, 256 threads ----
__global__ __launch_bounds__(256) void k_gemm(const float* __restrict__ X,
                                              const float* __restrict__ WT,   // [F][1024] f32
                                              const float* __restrict__ bias, // [1024] f32
                                              float* __restrict__ Z, int F){
  __shared__ float Xs[4][256];
  const int tid = threadIdx.x;
  const int m0 = blockIdx.x*4;
  for(int p=0;p<4;p++){
    int m = m0+p;
    for(int f=tid; f<F; f+=256)
      Xs[p][f] = (m < NM) ? X[m*F+f] : 0.0f;
  }
  __syncthreads();
  float acc0[4], acc1[4], acc2[4], acc3[4];
  {
    float b0 = bias[tid];
    float b1 = bias[tid+256];
    float b2 = bias[tid+512];
    float b3 = bias[tid+768];
    #pragma unroll
    for(int p=0;p<4;p++){ acc0[p]=b0; acc1[p]=b1; acc2[p]=b2; acc3[p]=b3; }
  }
  #pragma unroll 4
  for(int f=0; f<F; f++){
    float w0 = WT[f*1024 + tid      ];
    float w1 = WT[f*1024 + tid+256  ];
    float w2 = WT[f*1024 + tid+512  ];
    float w3 = WT[f*1024 + tid+768  ];
    #pragma unroll
    for(int p=0;p<4;p++){
      float xv = Xs[p][f];
      acc0[p] += w0*xv; acc1[p] += w1*xv; acc2[p] += w2*xv; acc3[p] += w3*xv;
    }
  }
  for(int p=0;p<4;p++){
    int m = m0+p;
    if(m < NM){
      float* zb = Z + m*1024 + tid;
      zb[0]=acc0[p]; zb[256]=acc1[p]; zb[512]=acc2[p]; zb[768]=acc3[p];
    }
  }
}

// ---- LSTM scan v5: one WG (512 thr) per chain; f16-pair Whh stream
// with v_dot2_f32_f16. Thread (kg = tid&127, js = tid>>7): k-slice
// js*64..+64, gate-rows {kg, kg+128, ..., kg+896} (strided -> lane-
// contiguous coalesced weight loads). h kept in LDS as f16 pairs.
__global__ __launch_bounds__(512) void k_scan5(
    const float* __restrict__ Z,
    const u32* __restrict__ WQ,   // packed f16-pair weights (512 KB)
    float* __restrict__ Y,
    const float* __restrict__ RES,
    int d){
  __shared__ u32   h16[128];             // 256 f16 h values (pairs)
  __shared__ float c_lds[256];
  __shared__ float zp[4][1024];
  const int tid = threadIdx.x;
  const int chain = blockIdx.x;
  const int j = chain % 10;
  const int r = chain / 10;
  const int ns = (273 - r + d - 1)/d;
  const int kg = tid & 127;
  const int js = tid >> 7;
  // per-thread base: uint4 index ((js*8+pq)*8+rr)*128 + kg
  const uint4* Wt = (const uint4*)WQ + (size_t)js*8192 + kg;
  const uint4* hq4 = (const uint4*)h16 + js*8;   // 8 uint4 per js-slice

  if(tid < 128) h16[tid] = 0u;
  if(tid < 256) c_lds[tid] = 0.0f;
  __syncthreads();

  int t = r;
  for(int s=0; s<ns; s++, t+=d){
    float a0=0,a1=0,a2=0,a3=0,a4=0,a5=0,a6=0,a7=0;
    #pragma unroll
    for(int pq=0;pq<8;pq++){
      uint4 hq = hq4[pq];                // 8 h halves (broadcast)
      const uint4* Wp = Wt + pq*1024;
      #pragma unroll
      for(int rr=0;rr<8;rr++){
        uint4 w = Wp[rr*128];
        float* ap = (rr==0)?&a0:(rr==1)?&a1:(rr==2)?&a2:(rr==3)?&a3:
                    (rr==4)?&a4:(rr==5)?&a5:(rr==6)?&a6:&a7;
        float acc = *ap;
        acc = dot2(w.x, hq.x, acc);
        acc = dot2(w.y, hq.y, acc);
        acc = dot2(w.z, hq.z, acc);
        acc = dot2(w.w, hq.w, acc);
        *ap = acc;
      }
    }
    zp[js][       kg] = a0;
    zp[js][128  + kg] = a1;
    zp[js][256  + kg] = a2;
    zp[js][384  + kg] = a3;
    zp[js][512  + kg] = a4;
    zp[js][640  + kg] = a5;
    zp[js][768  + kg] = a6;
    zp[js][896  + kg] = a7;
    __syncthreads();
    if(tid < 256){
      const int u = tid;
      const float* zb = Z + (size_t)(t*10 + j)*1024;
      float zi = zb[u]     + zp[0][u]     + zp[1][u]     + zp[2][u]     + zp[3][u];
      float zf = zb[u+256] + zp[0][u+256] + zp[1][u+256] + zp[2][u+256] + zp[3][u+256];
      float zg = zb[u+512] + zp[0][u+512] + zp[1][u+512] + zp[2][u+512] + zp[3][u+512];
      float zo = zb[u+768] + zp[0][u+768] + zp[1][u+768] + zp[2][u+768] + zp[3][u+768];
      float c  = sigf(zf)*c_lds[u] + sigf(zi)*tanh_(zg);
      float h  = sigf(zo)*tanh_(c);
      c_lds[u] = c;
      ((u16*)h16)[u] = __half_as_ushort(__float2half(h));
      float o = h;
      if(RES) o += RES[(size_t)(t*10+j)*256 + u];
      Y[(size_t)(t*10+j)*256 + u] = o;
    }
    __syncthreads();
  }
}

// ---- head: h = tanh(y4 @ linW.T + lb); rnn = h @ scW.T + sb ----
__global__ __launch_bounds__(256) void k_head(const float* __restrict__ Y4,
    const float* __restrict__ LWT,  // [256][256] f32 (linWT: [f][u])
    const float* __restrict__ lb,
    const float* __restrict__ SWT,  // [256][28] f32  (scoreT: [f][o])
    const float* __restrict__ sb,
    float* __restrict__ R){
  __shared__ float v [8][256];
  __shared__ float h2[8][256];
  const int tid = threadIdx.x;
  const int m0 = blockIdx.x*8;
  for(int p=0;p<8;p++){
    int m = m0+p;
    v[p][tid] = (m<NM) ? Y4[m*256+tid] : 0.0f;
  }
  __syncthreads();
  float acc[8];
  float bz = lb[tid];
  #pragma unroll
  for(int p=0;p<8;p++) acc[p]=bz;
  #pragma unroll 4
  for(int f=0; f<256; f++){
    float w = LWT[f*256+tid];
    #pragma unroll
    for(int p=0;p<8;p++) acc[p] += w * v[p][f];
  }
  #pragma unroll
  for(int p=0;p<8;p++) h2[p][tid] = tanh_(acc[p]);
  __syncthreads();
  if(tid < 224){
    int o = tid % 28, p = tid / 28;
    int m = m0 + p;
    if(m < NM){
      float a = sb[o];
      for(int f=0; f<256; f++) a += SWT[f*28+o] * h2[p][f];
      R[m*28+o] = a;
    }
  }
}

// ---- final outputs (f32) ----
// S_ext = concat(S_full[0:307], S_full[300:307]); S_ext[-28:][o] =
//   S_full[286+o] (o<21) else S_full[279+o]
__global__ void k_out(const float* __restrict__ R, const float* __restrict__ ST,
                      const float* __restrict__ lvlT, const float* __restrict__ val,
                      float* __restrict__ out){
  int i = blockIdx.x*256 + threadIdx.x;
  float* o0 = out;                 // prediction_values (245,128,28)
  float* o2 = out + 1756160;       // holdout_prediction (128,28)
  float* o3 = out + 1759744;       // rnn_out (273,128,28)
  float* o4 = out + 2738176;       // hav (128,28)
  float* o5 = out + 2741760;       // hav_norm (128,28)
  if(i < N_O3){
    int o = i % 28;
    int b = (i/28) % 128;
    int t = i/(28*128);
    float vv = R[(t*10 + (b%10))*28 + o];
    o3[i] = vv;
    if(i < N_O0) o0[i] = vv;       // rnn_out[:-OUT], same linear layout
  }
  if(i < 128*28){
    int b = i/28, o = i%28;
    int col = (o < 21) ? (286+o) : (279+o);
    float Sm = ST[col*128 + b];
    float lv = lvlT[299*128 + b];
    float hv = R[(2720 + (b%10))*28 + o] * Sm * lv;
    o2[i] = (hv > 0.0f) ? hv : 0.0f;
    o4[i] = val[i];
    o5[i] = val[i] / Sm / lv;
  }
}

extern "C" void kernel_launch(void* const* d_in, const int* in_sizes, int n_in,
                              void* d_out, int out_size, void* d_ws, size_t ws_size,
                              hipStream_t stream){
  (void)in_sizes; (void)n_in; (void)out_size; (void)ws_size;
  const float* x     = (const float*)d_in[0];
  const float* val   = (const float*)d_in[1];
  const float* alpha = (const float*)d_in[2];
  const float* gamma = (const float*)d_in[3];
  const float* iseas = (const float*)d_in[4];
  const float* cats  = (const float*)d_in[5];
  const float* mp    = (const float*)d_in[6];
  const float* Wih[4]  = {(const float*)d_in[7],  (const float*)d_in[10], (const float*)d_in[13], (const float*)d_in[16]};
  const float* Whh[4]  = {(const float*)d_in[8],  (const float*)d_in[11], (const float*)d_in[14], (const float*)d_in[17]};
  const float* bias[4] = {(const float*)d_in[9],  (const float*)d_in[12], (const float*)d_in[15], (const float*)d_in[18]};
  const float* linW  = (const float*)d_in[19];
  const float* linb  = (const float*)d_in[20];
  const float* scW   = (const float*)d_in[21];
  const float* scb   = (const float*)d_in[22];

  // ---- workspace layout: f32 region, then u32 packed-weight region ----
  float* Fw   = (float*)d_ws;
  float* ST   = Fw;                 // 39296
  float* lvlT = ST   + 39296;       // 38400
  float* xT   = lvlT + 38400;       // 38400
  float* win  = xT   + 38400;       // 133776
  float* xz   = win  + 133776;      // 2795520
  float* yA   = xz   + 2795520;     // 698880  (L1 out / L3 out / L4 out)
  float* yB   = yA   + 698880;      // 698880  (L2 out, residual)
  float* rnn  = yB   + 698880;      // 76448
  float* wihT[4];
  wihT[0] = rnn + 76448;            // 50176
  wihT[1] = wihT[0] + 50176;        // 262144
  wihT[2] = wihT[1] + 262144;
  wihT[3] = wihT[2] + 262144;
  float* linWT = wihT[3] + 262144;  // 65536
  float* scT   = linWT + 65536;     // 7168
  u32*   WQ[4];
  WQ[0] = (u32*)(scT + 7168);
  for(int l=1;l<4;l++) WQ[l] = WQ[l-1] + 131072;   // 4 * 512 KB

  // ---- weight prep ----
  for(int l=0;l<4;l++)
    k_pack<<<512, 256, 0, stream>>>(Whh[l], WQ[l]);
  k_trf<<<(1024*49+255)/256, 256, 0, stream>>>(Wih[0], wihT[0], 1024, 49);
  for(int l=1;l<4;l++)
    k_trf<<<(262144+255)/256, 256, 0, stream>>>(Wih[l], wihT[l], 1024, 256);
  k_trf<<<(65536+255)/256, 256, 0, stream>>>(linW, linWT, 256, 256);
  k_trf<<<(7168+255)/256, 256, 0, stream>>>(scW, scT, 28, 256);

  // ---- ES scan + windows ----
  k_xT<<<150, 256, 0, stream>>>(x, xT);
  k_es<<<1, 128, 0, stream>>>(xT, alpha, gamma, iseas, ST, lvlT);
  k_win<<<(NM*49+255)/256, 256, 0, stream>>>(xT, ST, lvlT, cats, mp, win);
  k_wout<<<N_O0/256, 256, 0, stream>>>(xT, ST, lvlT, (float*)d_out + 878080);

  // ---- 4 LSTM layers: batched Wih GEMM + f16-dot2 stream scan ----
  const int    dlt[4]    = {1, 2, 2, 6};
  const int    chains[4] = {10, 20, 20, 60};
  const float* Xin[4]    = {win, yA, yB, yA};
  float*       Yout[4]   = {yA, yB, yA, yA};
  const int    Fdim[4]   = {49, 256, 256, 256};
  for(int l=0;l<4;l++){
    k_gemm<<<(NM+3)/4, 256, 0, stream>>>(Xin[l], wihT[l], bias[l], xz, Fdim[l]);
    k_scan5<<<chains[l], 512, 0, stream>>>(xz, WQ[l], Yout[l],
                                           (l==3) ? yB : (const float*)nullptr, dlt[l]);
  }

  // ---- head + outputs ----
  k_head<<<(NM+7)/8, 256, 0, stream>>>(yA, linWT, linb, scT, scb, rnn);
  k_out<<<N_O3/256, 256, 0, stream>>>(rnn, ST, lvlT, val, (float*)d_out);
}

// Round 9
// 1131.519 us; speedup vs baseline: 10.4044x; 2.0701x over previous
//
#include <hip/hip_runtime.h>
#include <hip/hip_fp16.h>

typedef unsigned short u16;
typedef unsigned int   u32;

static __device__ __forceinline__ float sigf (float x){ return 1.0f/(1.0f+__expf(-x)); }
static __device__ __forceinline__ float tanh_(float x){ return 2.0f/(1.0f+__expf(-2.0f*x)) - 1.0f; }

// sizes
#define NM 2730            // 273*10 distinct (t, j=b%10) rows
#define N_O0 878080        // 245*128*28
#define N_O3 978432        // 273*128*28

static __device__ __forceinline__ int dot4(u32 w, u32 h, int acc){
#if __has_builtin(__builtin_amdgcn_sdot4)
  return __builtin_amdgcn_sdot4((int)w, (int)h, acc, false);
#else
  int s = acc;
  #pragma unroll
  for(int b=0;b<4;b++){
    int wv = (int)((signed char)((w >> (8*b)) & 0xffu));
    int hv = (int)((signed char)((h >> (8*b)) & 0xffu));
    s += wv*hv;
  }
  return s;
#endif
}

// ---- transpose f32 -> f32: dst[c*rows+r] = src[r*cols+c] ----
__global__ void k_trf(const float* __restrict__ src, float* __restrict__ dst, int rows, int cols){
  int i = blockIdx.x*256 + threadIdx.x;
  if(i >= rows*cols) return;
  int c = i / rows, r = i - c*rows;
  dst[i] = src[r*cols + c];
}

// ---- per-row absmax scale: zsc[row] = max|W[row][:]| / (127*127) ----
__global__ void k_scale(const float* __restrict__ W, float* __restrict__ zsc){
  int r = blockIdx.x*256 + threadIdx.x;
  if(r >= 1024) return;
  const float4* p = (const float4*)(W + (size_t)r*256);
  float m = 0.f;
  #pragma unroll 8
  for(int i=0;i<64;i++){
    float4 v = p[i];
    m = fmaxf(m, fmaxf(fmaxf(fabsf(v.x),fabsf(v.y)), fmaxf(fabsf(v.z),fabsf(v.w))));
  }
  zsc[r] = fmaxf(m, 1e-20f) * (1.0f/16129.0f);
}

// ---- pack Whh[1024][256] f32 -> int8 scan layout ----
// u32 i: dw=i&3, kg=(i>>2)&127, q=(i>>9)&3, rr=(i>>11)&7, js=i>>14
// row = rr*128+kg ; k0 = js*64 + q*16 + dw*4 ; bytes = k0..k0+3
__global__ void k_pack8(const float* __restrict__ W, const float* __restrict__ zsc,
                        u32* __restrict__ W8){
  int i = blockIdx.x*256 + threadIdx.x;
  if(i >= 65536) return;
  int dw = i & 3;
  int kg = (i >> 2) & 127;
  int q  = (i >> 9) & 3;
  int rr = (i >> 11) & 7;
  int js = i >> 14;
  int row = rr*128 + kg;
  int k0  = js*64 + q*16 + dw*4;
  float inv = 1.0f / (zsc[row] * 127.0f);
  u32 out = 0;
  #pragma unroll
  for(int b=0;b<4;b++){
    float v = W[(size_t)row*256 + k0 + b];
    int q8 = __float2int_rn(v * inv);
    q8 = max(-127, min(127, q8));
    out |= ((u32)(q8 & 0xff)) << (8*b);
  }
  W8[i] = out;
}

// ---- x (128,300) f32 -> xT[t*128+b] f32 ----
__global__ void k_xT(const float* __restrict__ x, float* __restrict__ xT){
  int i = blockIdx.x*256 + threadIdx.x;
  if(i >= 300*128) return;
  int t = i >> 7, b = i & 127;
  xT[i] = x[b*300 + t];
}

// ---- exponential-smoothing scan: 128 threads, one per batch row ----
__global__ void k_es(const float* __restrict__ xT, const float* __restrict__ alpha,
                     const float* __restrict__ gamma, const float* __restrict__ iseas,
                     float* __restrict__ ST, float* __restrict__ lvlT){
  int b = threadIdx.x;
  float a = sigf(alpha[b]);
  float g = sigf(gamma[b]);
  float S0[7];
  #pragma unroll
  for(int i=0;i<7;i++){ S0[i] = __expf(iseas[b*7+i]); ST[i*128+b] = S0[i]; }
  ST[7*128+b] = S0[0];
  float q0=S0[1],q1=S0[2],q2=S0[3],q3=S0[4],q4=S0[5],q5=S0[6],q6=S0[0];
  float lvl = xT[b]/S0[0];
  lvlT[b] = lvl;
  for(int t=1;t<300;t++){
    float xt = xT[t*128+b];
    float s  = q0;
    lvl = a*(xt/s) + (1.0f-a)*lvl;
    float sn = g*(xt/lvl) + (1.0f-g)*s;
    q0=q1;q1=q2;q2=q3;q3=q4;q4=q5;q5=q6;q6=sn;
    lvlT[t*128+b]   = lvl;
    ST[(t+7)*128+b] = sn;
  }
}

// ---- build window_input for the 10 distinct rows: win[(t*10+j)*49 + f] ----
__global__ void k_win(const float* __restrict__ xT, const float* __restrict__ ST,
                      const float* __restrict__ lvlT, const float* __restrict__ cats,
                      const float* __restrict__ mp, float* __restrict__ win){
  int i = blockIdx.x*256 + threadIdx.x;
  if(i >= NM*49) return;
  int f = i % 49;
  int m = i / 49;
  int j = m % 10, t = m / 10;
  float v;
  if(f < 28){
    int c = t + f;
    v = xT[c*128 + j] / ST[c*128 + j] / lvlT[(t+27)*128 + j];
  } else if(f < 48){
    v = cats[j*20 + (f-28)];
  } else {
    v = mp[0];
  }
  win[i] = v;
}

// ---- actual_values (window_output), per real batch row b (f32 out) ----
__global__ void k_wout(const float* __restrict__ xT, const float* __restrict__ ST,
                       const float* __restrict__ lvlT, float* __restrict__ out1){
  int i = blockIdx.x*256 + threadIdx.x;
  if(i >= N_O0) return;
  int o = i % 28;
  int b = (i/28) % 128;
  int t = i/(28*128);
  int c = 28 + t + o;                    // L + t + o  (<= 299)
  out1[i] = xT[c*128+b] / ST[c*128+b] / lvlT[(27+t)*128+b];
}

// ---- batched xz = X @ WihT + b : block = 4 rows x 1024 gates, 256 threads ----
__global__ __launch_bounds__(256) void k_gemm(const float* __restrict__ X,
                                              const float* __restrict__ WT,   // [F][1024] f32
                                              const float* __restrict__ bias, // [1024] f32
                                              float* __restrict__ Z, int F){
  __shared__ float Xs[4][256];
  const int tid = threadIdx.x;
  const int m0 = blockIdx.x*4;
  for(int p=0;p<4;p++){
    int m = m0+p;
    for(int f=tid; f<F; f+=256)
      Xs[p][f] = (m < NM) ? X[m*F+f] : 0.0f;
  }
  __syncthreads();
  float acc0[4], acc1[4], acc2[4], acc3[4];
  {
    float b0 = bias[tid];
    float b1 = bias[tid+256];
    float b2 = bias[tid+512];
    float b3 = bias[tid+768];
    #pragma unroll
    for(int p=0;p<4;p++){ acc0[p]=b0; acc1[p]=b1; acc2[p]=b2; acc3[p]=b3; }
  }
  #pragma unroll 4
  for(int f=0; f<F; f++){
    float w0 = WT[f*1024 + tid      ];
    float w1 = WT[f*1024 + tid+256  ];
    float w2 = WT[f*1024 + tid+512  ];
    float w3 = WT[f*1024 + tid+768  ];
    #pragma unroll
    for(int p=0;p<4;p++){
      float xv = Xs[p][f];
      acc0[p] += w0*xv; acc1[p] += w1*xv; acc2[p] += w2*xv; acc3[p] += w3*xv;
    }
  }
  for(int p=0;p<4;p++){
    int m = m0+p;
    if(m < NM){
      float* zb = Z + m*1024 + tid;
      zb[0]=acc0[p]; zb[256]=acc1[p]; zb[512]=acc2[p]; zb[768]=acc3[p];
    }
  }
}

// ---- LSTM scan v6: one WG (512 thr) per chain; int8 Whh stream with
// v_dot4_i32_i8, per-row weight scales (LDS), h as int8 fixed-scale 127
// (valid: |h| < 1 always). Thread (kg=tid&127, js=tid>>7): k-slice
// js*64..+64, gate-rows {kg, kg+128, ..., kg+896}. 256 KB/step stream.
__global__ __launch_bounds__(512) void k_scan6(
    const float* __restrict__ Z,
    const u32* __restrict__ W8,    // packed int8 weights (256 KB)
    const float* __restrict__ zsc, // [1024] per-row z scales
    float* __restrict__ Y,
    const float* __restrict__ RES,
    int d){
  __shared__ u32   h8[64];               // 256 int8 h values
  __shared__ int   zp[4][1024];          // 16 KB partial dots
  __shared__ float sc[1024];             // 4 KB row scales
  const int tid = threadIdx.x;
  const int chain = blockIdx.x;
  const int j = chain % 10;
  const int r = chain / 10;
  const int ns = (273 - r + d - 1)/d;
  const int kg = tid & 127;
  const int js = tid >> 7;
  // uint4 index: ((js*8+rr)*4+q)*128 + kg = js*4096 + rr*512 + q*128 + kg
  const uint4* Wb = (const uint4*)W8 + (size_t)js*4096 + kg;
  const uint4* hq = (const uint4*)h8 + js*4;   // 4 uint4 per js-slice

  for(int i=tid;i<1024;i+=512) sc[i] = zsc[i];
  if(tid < 64) h8[tid] = 0u;
  float cst = 0.0f;                      // c-state (threads 0..255)
  __syncthreads();

  int t = r;
  for(int s=0; s<ns; s++, t+=d){
    int a0=0,a1=0,a2=0,a3=0,a4=0,a5=0,a6=0,a7=0;
    #pragma unroll
    for(int q=0;q<4;q++){
      uint4 h4 = hq[q];                  // broadcast: 16 h int8
      const uint4* Wp = Wb + q*128;
      #pragma unroll
      for(int rr=0;rr<8;rr++){
        uint4 w = Wp[rr*512];
        int* ap = (rr==0)?&a0:(rr==1)?&a1:(rr==2)?&a2:(rr==3)?&a3:
                  (rr==4)?&a4:(rr==5)?&a5:(rr==6)?&a6:&a7;
        int acc = *ap;
        acc = dot4(w.x, h4.x, acc);
        acc = dot4(w.y, h4.y, acc);
        acc = dot4(w.z, h4.z, acc);
        acc = dot4(w.w, h4.w, acc);
        *ap = acc;
      }
    }
    zp[js][       kg] = a0;
    zp[js][128  + kg] = a1;
    zp[js][256  + kg] = a2;
    zp[js][384  + kg] = a3;
    zp[js][512  + kg] = a4;
    zp[js][640  + kg] = a5;
    zp[js][768  + kg] = a6;
    zp[js][896  + kg] = a7;
    __syncthreads();
    if(tid < 256){
      const int u = tid;
      const float* zb = Z + (size_t)(t*10 + j)*1024;
      int si = zp[0][u]     + zp[1][u]     + zp[2][u]     + zp[3][u];
      int sf = zp[0][u+256] + zp[1][u+256] + zp[2][u+256] + zp[3][u+256];
      int sg = zp[0][u+512] + zp[1][u+512] + zp[2][u+512] + zp[3][u+512];
      int so = zp[0][u+768] + zp[1][u+768] + zp[2][u+768] + zp[3][u+768];
      float zi = zb[u]     + sc[u]     * (float)si;
      float zf = zb[u+256] + sc[u+256] * (float)sf;
      float zg = zb[u+512] + sc[u+512] * (float)sg;
      float zo = zb[u+768] + sc[u+768] * (float)so;
      float c  = sigf(zf)*cst + sigf(zi)*tanh_(zg);
      float h  = sigf(zo)*tanh_(c);
      cst = c;
      int hqi = __float2int_rn(h * 127.0f);
      hqi = max(-127, min(127, hqi));
      ((signed char*)h8)[u] = (signed char)hqi;
      float o = h;
      if(RES) o += RES[(size_t)(t*10+j)*256 + u];
      Y[(size_t)(t*10+j)*256 + u] = o;
    }
    __syncthreads();
  }
}

// ---- head: h = tanh(y4 @ linW.T + lb); rnn = h @ scW.T + sb ----
__global__ __launch_bounds__(256) void k_head(const float* __restrict__ Y4,
    const float* __restrict__ LWT,  // [256][256] f32 (linWT: [f][u])
    const float* __restrict__ lb,
    const float* __restrict__ SWT,  // [256][28] f32  (scoreT: [f][o])
    const float* __restrict__ sb,
    float* __restrict__ R){
  __shared__ float v [8][256];
  __shared__ float h2[8][256];
  const int tid = threadIdx.x;
  const int m0 = blockIdx.x*8;
  for(int p=0;p<8;p++){
    int m = m0+p;
    v[p][tid] = (m<NM) ? Y4[m*256+tid] : 0.0f;
  }
  __syncthreads();
  float acc[8];
  float bz = lb[tid];
  #pragma unroll
  for(int p=0;p<8;p++) acc[p]=bz;
  #pragma unroll 4
  for(int f=0; f<256; f++){
    float w = LWT[f*256+tid];
    #pragma unroll
    for(int p=0;p<8;p++) acc[p] += w * v[p][f];
  }
  #pragma unroll
  for(int p=0;p<8;p++) h2[p][tid] = tanh_(acc[p]);
  __syncthreads();
  if(tid < 224){
    int o = tid % 28, p = tid / 28;
    int m = m0 + p;
    if(m < NM){
      float a = sb[o];
      for(int f=0; f<256; f++) a += SWT[f*28+o] * h2[p][f];
      R[m*28+o] = a;
    }
  }
}

// ---- final outputs (f32) ----
// S_ext = concat(S_full[0:307], S_full[300:307]); S_ext[-28:][o] =
//   S_full[286+o] (o<21) else S_full[279+o]
__global__ void k_out(const float* __restrict__ R, const float* __restrict__ ST,
                      const float* __restrict__ lvlT, const float* __restrict__ val,
                      float* __restrict__ out){
  int i = blockIdx.x*256 + threadIdx.x;
  float* o0 = out;                 // prediction_values (245,128,28)
  float* o2 = out + 1756160;       // holdout_prediction (128,28)
  float* o3 = out + 1759744;       // rnn_out (273,128,28)
  float* o4 = out + 2738176;       // hav (128,28)
  float* o5 = out + 2741760;       // hav_norm (128,28)
  if(i < N_O3){
    int o = i % 28;
    int b = (i/28) % 128;
    int t = i/(28*128);
    float vv = R[(t*10 + (b%10))*28 + o];
    o3[i] = vv;
    if(i < N_O0) o0[i] = vv;       // rnn_out[:-OUT], same linear layout
  }
  if(i < 128*28){
    int b = i/28, o = i%28;
    int col = (o < 21) ? (286+o) : (279+o);
    float Sm = ST[col*128 + b];
    float lv = lvlT[299*128 + b];
    float hv = R[(2720 + (b%10))*28 + o] * Sm * lv;
    o2[i] = (hv > 0.0f) ? hv : 0.0f;
    o4[i] = val[i];
    o5[i] = val[i] / Sm / lv;
  }
}

extern "C" void kernel_launch(void* const* d_in, const int* in_sizes, int n_in,
                              void* d_out, int out_size, void* d_ws, size_t ws_size,
                              hipStream_t stream){
  (void)in_sizes; (void)n_in; (void)out_size; (void)ws_size;
  const float* x     = (const float*)d_in[0];
  const float* val   = (const float*)d_in[1];
  const float* alpha = (const float*)d_in[2];
  const float* gamma = (const float*)d_in[3];
  const float* iseas = (const float*)d_in[4];
  const float* cats  = (const float*)d_in[5];
  const float* mp    = (const float*)d_in[6];
  const float* Wih[4]  = {(const float*)d_in[7],  (const float*)d_in[10], (const float*)d_in[13], (const float*)d_in[16]};
  const float* Whh[4]  = {(const float*)d_in[8],  (const float*)d_in[11], (const float*)d_in[14], (const float*)d_in[17]};
  const float* bias[4] = {(const float*)d_in[9],  (const float*)d_in[12], (const float*)d_in[15], (const float*)d_in[18]};
  const float* linW  = (const float*)d_in[19];
  const float* linb  = (const float*)d_in[20];
  const float* scW   = (const float*)d_in[21];
  const float* scb   = (const float*)d_in[22];

  // ---- workspace layout: f32 region, then u32 packed-weight region ----
  float* Fw   = (float*)d_ws;
  float* ST   = Fw;                 // 39296
  float* lvlT = ST   + 39296;       // 38400
  float* xT   = lvlT + 38400;       // 38400
  float* win  = xT   + 38400;       // 133776
  float* xz   = win  + 133776;      // 2795520
  float* yA   = xz   + 2795520;     // 698880  (L1 out / L3 out / L4 out)
  float* yB   = yA   + 698880;      // 698880  (L2 out, residual)
  float* rnn  = yB   + 698880;      // 76448
  float* wihT[4];
  wihT[0] = rnn + 76448;            // 50176
  wihT[1] = wihT[0] + 50176;        // 262144
  wihT[2] = wihT[1] + 262144;
  wihT[3] = wihT[2] + 262144;
  float* linWT = wihT[3] + 262144;  // 65536
  float* scT   = linWT + 65536;     // 7168
  float* zsc[4];
  zsc[0] = scT + 7168;
  for(int l=1;l<4;l++) zsc[l] = zsc[l-1] + 1024;
  u32* W8[4];
  W8[0] = (u32*)(zsc[3] + 1024);
  for(int l=1;l<4;l++) W8[l] = W8[l-1] + 65536;     // 4 * 256 KB

  // ---- weight prep ----
  for(int l=0;l<4;l++){
    k_scale<<<4, 256, 0, stream>>>(Whh[l], zsc[l]);
    k_pack8<<<256, 256, 0, stream>>>(Whh[l], zsc[l], W8[l]);
  }
  k_trf<<<(1024*49+255)/256, 256, 0, stream>>>(Wih[0], wihT[0], 1024, 49);
  for(int l=1;l<4;l++)
    k_trf<<<(262144+255)/256, 256, 0, stream>>>(Wih[l], wihT[l], 1024, 256);
  k_trf<<<(65536+255)/256, 256, 0, stream>>>(linW, linWT, 256, 256);
  k_trf<<<(7168+255)/256, 256, 0, stream>>>(scW, scT, 28, 256);

  // ---- ES scan + windows ----
  k_xT<<<150, 256, 0, stream>>>(x, xT);
  k_es<<<1, 128, 0, stream>>>(xT, alpha, gamma, iseas, ST, lvlT);
  k_win<<<(NM*49+255)/256, 256, 0, stream>>>(xT, ST, lvlT, cats, mp, win);
  k_wout<<<N_O0/256, 256, 0, stream>>>(xT, ST, lvlT, (float*)d_out + 878080);

  // ---- 4 LSTM layers: batched Wih GEMM + int8-dot4 stream scan ----
  const int    dlt[4]    = {1, 2, 2, 6};
  const int    chains[4] = {10, 20, 20, 60};
  const float* Xin[4]    = {win, yA, yB, yA};
  float*       Yout[4]   = {yA, yB, yA, yA};
  const int    Fdim[4]   = {49, 256, 256, 256};
  for(int l=0;l<4;l++){
    k_gemm<<<(NM+3)/4, 256, 0, stream>>>(Xin[l], wihT[l], bias[l], xz, Fdim[l]);
    k_scan6<<<chains[l], 512, 0, stream>>>(xz, W8[l], zsc[l], Yout[l],
                                           (l==3) ? yB : (const float*)nullptr, dlt[l]);
  }

  // ---- head + outputs ----
  k_head<<<(NM+7)/8, 256, 0, stream>>>(yA, linWT, linb, scT, scb, rnn);
  k_out<<<N_O3/256, 256, 0, stream>>>(rnn, ST, lvlT, val, (float*)d_out);
}